// Round 12
// baseline (123.984 us; speedup 1.0000x reference)
//
#include <hip/hip_runtime.h>
#include <hip/hip_bf16.h>

typedef __bf16 bf16x8 __attribute__((ext_vector_type(8)));
typedef float  f32x4  __attribute__((ext_vector_type(4)));

#define B_SZ 4096
#define I_SZ 512
#define O_SZ 64
#define E_SZ 128
#define BM   256
#define G_EXP 8      // experts per workgroup (K-split group size)
#define EG_N  16     // expert groups
#define MT_N  16     // m tiles (4096/256)

// ---------------- fused prep: x f32->bf16  +  gT[e][b] ----------------
__global__ void prep_xg(const float* __restrict__ x, __bf16* __restrict__ xb,
                        const float* __restrict__ ds, const float* __restrict__ ts,
                        float* __restrict__ gT) {
  int i = blockIdx.x * 256 + threadIdx.x;          // 524288 = B*I/4 = E*B
  float4 v = ((const float4*)x)[i];
  union { __bf16 h[4]; ushort4 u4; } pk;
  pk.h[0] = (__bf16)v.x; pk.h[1] = (__bf16)v.y;
  pk.h[2] = (__bf16)v.z; pk.h[3] = (__bf16)v.w;
  ((ushort4*)xb)[i] = pk.u4;
  int e = i >> 12, b = i & 4095;
  gT[i] = ds[b * 32 + (e >> 2)] * ts[b * 4 + (e & 3)];
}

// ---------------- prep: W [e][i][o] f32 -> wt [e][o][i] bf16 ----------------
__global__ void prep_w(const float* __restrict__ W, __bf16* __restrict__ wt) {
  __shared__ __bf16 tile[64][66];
  int e  = blockIdx.x >> 3;
  int it = blockIdx.x & 7;
  const float* src = W + (size_t)e * I_SZ * O_SZ + (size_t)it * 64 * O_SZ;
  #pragma unroll
  for (int s = 0; s < 16; ++s) {
    int idx = s * 256 + threadIdx.x;
    int r = idx >> 6, o = idx & 63;
    tile[o][r] = (__bf16)src[idx];
  }
  __syncthreads();
  __bf16* dst = wt + (size_t)e * O_SZ * I_SZ + it * 64;
  #pragma unroll
  for (int s = 0; s < 4; ++s) {
    int idx = s * 256 + threadIdx.x;
    int o = idx >> 4, c = (idx & 15) << 2;
    union { __bf16 h[4]; ushort4 u4; } q;
    q.h[0] = tile[o][c + 0]; q.h[1] = tile[o][c + 1];
    q.h[2] = tile[o][c + 2]; q.h[3] = tile[o][c + 3];
    *(ushort4*)&dst[(size_t)o * I_SZ + c] = q.u4;
  }
}

// ---------------- main: 64-row waves via K-split wave pairs -------------------
// 8 waves = 4 row-groups(64 rows) x 2 K-halves(K=256). Each wave reads only its
// K-half of W from LDS (32KB/expert, HALF of R9) while af stays 128 VGPR -> 2
// waves/SIMD. Gating is linear in K-partials: each wave accumulates gated
// logits^kh independently; ONE epilogue exchange via dead wsh[0]. nf-outer loop
// with immediate drain keeps live regs ~245 < 256. Chunked zero-conflict LDS,
// 2 barriers + counted vmcnt(8)/expert, bias folded in kh=0 only.
__global__ __launch_bounds__(512, 2)
void mtc_gemm(const __bf16* __restrict__ xb, const __bf16* __restrict__ wt,
              const float* __restrict__ gT, const float* __restrict__ bias,
              float* __restrict__ partials) {
  __shared__ __align__(16) __bf16 wsh[2][8][64 * 64];  // [buf][kc][o*64+slot*8] 8KB chunks
  __shared__ float gsh[G_EXP][BM];                     // 8KB gates
  __shared__ float bsh[G_EXP][O_SZ];                   // 2KB bias

  const int tid  = threadIdx.x;
  const int wave = tid >> 6;
  const int lane = tid & 63;
  const int rg   = wave >> 1;                          // row-group: 64 rows
  const int kh   = wave & 1;                           // K-half: 0 -> k<256, 1 -> k>=256

  // XCD swizzle: 256 blocks -> 32 consecutive per XCD
  int bid = (int)blockIdx.x;
  bid = (bid & 7) * 32 + (bid >> 3);
  const int mtile = bid & 15;
  const int eg    = bid >> 4;
  const int row0  = mtile * BM;
  const int e0    = eg * G_EXP;

  // stage whole expert e into wsh[sbuf]: 8 DMAs/thread (512 thr x 16B x 8 = 64KB).
  // dest linear => [o=tid>>3][slot p=tid&7]; source slot sl = p^(o&7) (involution).
  auto stage = [&](int sbuf, int e) {
    const __bf16* wsrc = wt + (size_t)(e0 + e) * O_SZ * I_SZ;
    int o = tid >> 3, p = tid & 7;
    int sl = p ^ (o & 7);
    #pragma unroll
    for (int kc = 0; kc < 8; ++kc) {
      __builtin_amdgcn_global_load_lds(
          (const __attribute__((address_space(1))) void*)(wsrc + (size_t)o * I_SZ + kc * 64 + sl * 8),
          (__attribute__((address_space(3))) void*)(&wsh[sbuf][kc][(tid >> 6) * 512]),
          16, 0, 0);
    }
  };

  // prologue: stage expert 0, overlap with gsh + bias + af loads
  stage(0, 0);

  for (int idx = tid; idx < G_EXP * BM; idx += 512)
    gsh[idx >> 8][idx & 255] =
        gT[(size_t)(e0 + (idx >> 8)) * B_SZ + row0 + (idx & 255)];

  bsh[tid >> 6][tid & 63] = bias[(size_t)e0 * O_SZ + tid];   // 512 = G_EXP*O_SZ

  // af[mf][j] = x[row0 + rg*64 + mf*16 + (lane&15)][kh*256 + j*32 + (lane>>4)*8 ..+8]
  bf16x8 af[4][8];                                   // 128 VGPR
  {
    const __bf16* xr = xb + (size_t)(row0 + rg * 64 + (lane & 15)) * I_SZ
                          + kh * 256 + (lane >> 4) * 8;
    #pragma unroll
    for (int mf = 0; mf < 4; ++mf)
      #pragma unroll
      for (int j = 0; j < 8; ++j)
        af[mf][j] = *(const bf16x8*)(xr + mf * 16 * I_SZ + j * 32);
  }

  __syncthreads();                     // drains DMA(e0) + af + bias + gsh

  f32x4 logits[4][4] = {};             // 64 VGPR (this wave's gated K-half partial)
  int buf = 0;
  for (int e = 0; e < G_EXP; ++e) {
    if (e < G_EXP - 1) {
      stage(buf ^ 1, e + 1);                       // 8 DMAs into other buffer
      asm volatile("s_waitcnt vmcnt(8)" ::: "memory");   // stage(e) landed
    } else {
      asm volatile("s_waitcnt vmcnt(0)" ::: "memory");
    }
    __builtin_amdgcn_s_barrier();                  // buf ready for all waves

    #pragma unroll
    for (int nf = 0; nf < 4; ++nf) {               // nf-outer: acc only 16 regs live
      float bv = kh ? 0.f : bsh[e][nf * 16 + (lane & 15)];  // bias once (kh=0)
      f32x4 acc[4];
      #pragma unroll
      for (int mf = 0; mf < 4; ++mf)
        acc[mf] = (f32x4){bv, bv, bv, bv};

      __builtin_amdgcn_s_setprio(1);
      #pragma unroll
      for (int j = 0; j < 8; ++j) {                // this wave's K-half: 8 K32-steps
        const __bf16* wb = &wsh[buf][kh * 4 + (j >> 1)][0];
        int o  = nf * 16 + (lane & 15);
        int q  = (j & 1) * 4 + (lane >> 4);
        int ph = q ^ (o & 7);
        bf16x8 bfr = *(const bf16x8*)(wb + o * 64 + ph * 8);
        #pragma unroll
        for (int mf = 0; mf < 4; ++mf)
          acc[mf] = __builtin_amdgcn_mfma_f32_16x16x32_bf16(
              af[mf][j], bfr, acc[mf], 0, 0, 0);
      }
      __builtin_amdgcn_s_setprio(0);

      // immediate drain: logits += g * acc   (C/D: col=lane&15, row=(lane>>4)*4+rg)
      #pragma unroll
      for (int mf = 0; mf < 4; ++mf) {
        f32x4 gq = *(const f32x4*)&gsh[e][rg * 64 + mf * 16 + (lane >> 4) * 4];
        #pragma unroll
        for (int rgi = 0; rgi < 4; ++rgi)
          logits[mf][nf][rgi] += gq[rgi] * acc[mf][rgi];
      }
    }

    __builtin_amdgcn_s_barrier();                  // all waves done reading buf
    buf ^= 1;
  }

  // ---- epilogue: sum the two K-half partials per row-group via dead wsh[0] ----
  // layout [rg][reg16][lane] x 16B: lane-contiguous 1KB rows -> conflict-free b128.
  float* exch = (float*)&wsh[0][0][0];             // 64KB, free (last expert used buf 1)
  if (kh) {
    #pragma unroll
    for (int mf = 0; mf < 4; ++mf)
      #pragma unroll
      for (int nf = 0; nf < 4; ++nf)
        *(f32x4*)&exch[rg * 4096 + (mf * 4 + nf) * 256 + lane * 4] = logits[mf][nf];
  }
  __syncthreads();
  if (!kh) {
    float* pout = partials + (size_t)eg * B_SZ * O_SZ + (size_t)row0 * O_SZ;
    #pragma unroll
    for (int mf = 0; mf < 4; ++mf)
      #pragma unroll
      for (int nf = 0; nf < 4; ++nf) {
        f32x4 other = *(const f32x4*)&exch[rg * 4096 + (mf * 4 + nf) * 256 + lane * 4];
        #pragma unroll
        for (int rgi = 0; rgi < 4; ++rgi) {
          int r = rg * 64 + mf * 16 + ((lane >> 4) << 2) + rgi;
          int o = nf * 16 + (lane & 15);
          pout[(size_t)r * O_SZ + o] = logits[mf][nf][rgi] + other[rgi];
        }
      }
  }
}

// ---------------- reduce: sum partials + log_softmax (bias already in gemm) ----
__global__ __launch_bounds__(256)
void mtc_reduce(const float* __restrict__ partials, float* __restrict__ out) {
  int wave = threadIdx.x >> 6, lane = threadIdx.x & 63;
  int r = blockIdx.x * 4 + wave;                    // one 64-lane wave per row
  float s = 0.f;
  #pragma unroll
  for (int k = 0; k < EG_N; ++k)
    s += partials[(size_t)k * B_SZ * O_SZ + (size_t)r * O_SZ + lane];
  float m = s;
  #pragma unroll
  for (int off = 32; off; off >>= 1) m = fmaxf(m, __shfl_xor(m, off));
  float ex = expf(s - m), sum = ex;
  #pragma unroll
  for (int off = 32; off; off >>= 1) sum += __shfl_xor(sum, off);
  out[(size_t)r * O_SZ + lane] = s - m - logf(sum);
}

extern "C" void kernel_launch(void* const* d_in, const int* in_sizes, int n_in,
                              void* d_out, int out_size, void* d_ws, size_t ws_size,
                              hipStream_t stream) {
  const float* x    = (const float*)d_in[0];
  const float* ds   = (const float*)d_in[1];
  const float* ts   = (const float*)d_in[2];
  const float* W    = (const float*)d_in[3];
  const float* bias = (const float*)d_in[4];
  float* out = (float*)d_out;

  char* w = (char*)d_ws;
  __bf16* xb      = (__bf16*)(w);                   // 4 MB
  __bf16* wt      = (__bf16*)(w + (4ull  << 20));   // 8 MB
  float*  gT      = (float*) (w + (12ull << 20));   // 2 MB
  float*  parts   = (float*) (w + (14ull << 20));   // 16 MB

  prep_xg   <<<2048, 256, 0, stream>>>(x, xb, ds, ts, gT);
  prep_w    <<<1024, 256, 0, stream>>>(W, wt);
  mtc_gemm  <<< 256, 512, 0, stream>>>(xb, wt, gT, bias, parts);
  mtc_reduce<<<1024, 256, 0, stream>>>(parts, out);
}

// Round 13
// 57.863 us; speedup vs baseline: 2.1427x; 2.1427x over previous
//
#include <hip/hip_runtime.h>
#include <hip/hip_bf16.h>

typedef __bf16 bf16x8 __attribute__((ext_vector_type(8)));
typedef float  f32x4  __attribute__((ext_vector_type(4)));

#define B_SZ 4096
#define I_SZ 512
#define O_SZ 64
#define E_SZ 128
#define BM   256
#define G_EXP 8      // experts per workgroup (K-split group size)
#define EG_N  16     // expert groups
#define MT_N  16     // m tiles (4096/256)

// ---------------- fused prep: x f32->bf16  +  gT[e][b] ----------------
__global__ void prep_xg(const float* __restrict__ x, __bf16* __restrict__ xb,
                        const float* __restrict__ ds, const float* __restrict__ ts,
                        float* __restrict__ gT) {
  int i = blockIdx.x * 256 + threadIdx.x;          // 524288 = B*I/4 = E*B
  float4 v = ((const float4*)x)[i];
  union { __bf16 h[4]; ushort4 u4; } pk;
  pk.h[0] = (__bf16)v.x; pk.h[1] = (__bf16)v.y;
  pk.h[2] = (__bf16)v.z; pk.h[3] = (__bf16)v.w;
  ((ushort4*)xb)[i] = pk.u4;
  int e = i >> 12, b = i & 4095;
  gT[i] = ds[b * 32 + (e >> 2)] * ts[b * 4 + (e & 3)];
}

// ---------------- prep: W [e][i][o] f32 -> wt [e][o][i] bf16 ----------------
__global__ void prep_w(const float* __restrict__ W, __bf16* __restrict__ wt) {
  __shared__ __bf16 tile[64][66];
  int e  = blockIdx.x >> 3;
  int it = blockIdx.x & 7;
  const float* src = W + (size_t)e * I_SZ * O_SZ + (size_t)it * 64 * O_SZ;
  #pragma unroll
  for (int s = 0; s < 16; ++s) {
    int idx = s * 256 + threadIdx.x;
    int r = idx >> 6, o = idx & 63;
    tile[o][r] = (__bf16)src[idx];
  }
  __syncthreads();
  __bf16* dst = wt + (size_t)e * O_SZ * I_SZ + it * 64;
  #pragma unroll
  for (int s = 0; s < 4; ++s) {
    int idx = s * 256 + threadIdx.x;
    int o = idx >> 4, c = (idx & 15) << 2;
    union { __bf16 h[4]; ushort4 u4; } q;
    q.h[0] = tile[o][c + 0]; q.h[1] = tile[o][c + 1];
    q.h[2] = tile[o][c + 2]; q.h[3] = tile[o][c + 3];
    *(ushort4*)&dst[(size_t)o * I_SZ + c] = q.u4;
  }
}

// ---------------- main: R9 body + m201-style counted-vmcnt sub-phase pipeline --
// 8 waves x 32 rows (Mf=2 of 16) = BM 256; mfma_f32_16x16x32_bf16, Nf=4 covers O=64.
// Per expert: 4 sub-phases. Sub-phase s: {issue 2 DMAs for e+1 (chunks 2s,2s+1,
// FIFO) -> vmcnt(8) retires EXACTLY B_e[2s],B_e[2s+1] (the chunks read next) ->
// barrier -> 16 ds_read (chunks 2s,2s+1) -> setprio 32 MFMA}. Never drains to 0
// in steady state (m218: counted-vs-drain0 is THE lever); tail 6/4/2/0 at e=7
// only. Chunked zero-conflict LDS (R7), bias in LDS (R9), runtime e loop (no
// unroll -> no pressure blowup; R12's restructure spilled, reverted).
__global__ __launch_bounds__(512, 2)
void mtc_gemm(const __bf16* __restrict__ xb, const __bf16* __restrict__ wt,
              const float* __restrict__ gT, const float* __restrict__ bias,
              float* __restrict__ partials) {
  __shared__ __align__(16) __bf16 wsh[2][8][64 * 64];  // [buf][kc][o*64+slot*8] 8KB chunks
  __shared__ float gsh[G_EXP][BM];                     // 8KB gates
  __shared__ float bsh[G_EXP][O_SZ];                   // 2KB bias

  const int tid  = threadIdx.x;
  const int wave = tid >> 6;
  const int lane = tid & 63;

  // XCD swizzle: 256 blocks -> 32 consecutive per XCD
  int bid = (int)blockIdx.x;
  bid = (bid & 7) * 32 + (bid >> 3);
  const int mtile = bid & 15;
  const int eg    = bid >> 4;
  const int row0  = mtile * BM;
  const int e0    = eg * G_EXP;

  // DMA pair for chunks (2s, 2s+1) of expert e into wsh[sbuf] (FIFO chunk order).
  // dest linear => [o=tid>>3][slot p=tid&7]; source slot sl = p^(o&7) (involution).
  auto stage2 = [&](int sbuf, int e, int s) {
    const __bf16* wsrc = wt + (size_t)(e0 + e) * O_SZ * I_SZ;
    int o = tid >> 3, p = tid & 7;
    int sl = p ^ (o & 7);
    #pragma unroll
    for (int ii = 0; ii < 2; ++ii) {
      int kc = s * 2 + ii;
      __builtin_amdgcn_global_load_lds(
          (const __attribute__((address_space(1))) void*)(wsrc + (size_t)o * I_SZ + kc * 64 + sl * 8),
          (__attribute__((address_space(3))) void*)(&wsh[sbuf][kc][wave * 512]),
          16, 0, 0);
    }
  };

  // prologue: stage expert 0 fully, overlap with gsh + bias + af loads
  #pragma unroll
  for (int s = 0; s < 4; ++s) stage2(0, 0, s);

  for (int idx = tid; idx < G_EXP * BM; idx += 512)
    gsh[idx >> 8][idx & 255] =
        gT[(size_t)(e0 + (idx >> 8)) * B_SZ + row0 + (idx & 255)];

  bsh[tid >> 6][tid & 63] = bias[(size_t)e0 * O_SZ + tid];   // 512 = G_EXP*O_SZ

  // x A-fragments: af[mf][j] = x[row0+wave*32+mf*16+(lane&15)][j*32+(lane>>4)*8 ..+8]
  bf16x8 af[2][16];
  {
    const __bf16* xr = xb + (size_t)(row0 + wave * 32 + (lane & 15)) * I_SZ
                          + (lane >> 4) * 8;
    #pragma unroll
    for (int mf = 0; mf < 2; ++mf)
      #pragma unroll
      for (int j = 0; j < 16; ++j)
        af[mf][j] = *(const bf16x8*)(xr + mf * 16 * I_SZ + j * 32);
  }

  __syncthreads();                     // drains DMA(e0) + af + bias + gsh (vmcnt->0)

  f32x4 logits[2][4] = {};
  int buf = 0;
  for (int e = 0; e < G_EXP; ++e) {
    // bias -> acc init (LDS read, lgkm only)
    float bv[4];
    #pragma unroll
    for (int nf = 0; nf < 4; ++nf)
      bv[nf] = bsh[e][nf * 16 + (lane & 15)];
    f32x4 acc[2][4];
    #pragma unroll
    for (int mf = 0; mf < 2; ++mf)
      #pragma unroll
      for (int nf = 0; nf < 4; ++nf)
        acc[mf][nf] = (f32x4){bv[nf], bv[nf], bv[nf], bv[nf]};

    const __bf16* wb0 = &wsh[buf][0][0];
    const bool pf = (e < G_EXP - 1);
    #pragma unroll
    for (int s = 0; s < 4; ++s) {
      if (pf) {
        stage2(buf ^ 1, e + 1, s);               // issue 2 (FIFO)
        asm volatile("s_waitcnt vmcnt(8)" ::: "memory");   // retire B_e[2s,2s+1]
      } else {                                   // tail drain, last expert only
        if (s == 0) asm volatile("s_waitcnt vmcnt(6)" ::: "memory");
        if (s == 1) asm volatile("s_waitcnt vmcnt(4)" ::: "memory");
        if (s == 2) asm volatile("s_waitcnt vmcnt(2)" ::: "memory");
        if (s == 3) asm volatile("s_waitcnt vmcnt(0)" ::: "memory");
      }
      __builtin_amdgcn_s_barrier();              // chunks 2s,2s+1 ready for all

      __builtin_amdgcn_s_setprio(1);
      #pragma unroll
      for (int jj = 0; jj < 4; ++jj) {           // j = s*4+jj; chunk j>>1 in {2s,2s+1}
        const int j = s * 4 + jj;
        const __bf16* wb = wb0 + (j >> 1) * 4096;
        bf16x8 bfr[4];
        #pragma unroll
        for (int nf = 0; nf < 4; ++nf) {
          int o  = nf * 16 + (lane & 15);
          int q  = (j & 1) * 4 + (lane >> 4);
          int ph = q ^ (o & 7);
          bfr[nf] = *(const bf16x8*)(wb + o * 64 + ph * 8);
        }
        #pragma unroll
        for (int nf = 0; nf < 4; ++nf)
          #pragma unroll
          for (int mf = 0; mf < 2; ++mf)
            acc[mf][nf] = __builtin_amdgcn_mfma_f32_16x16x32_bf16(
                af[mf][j], bfr[nf], acc[mf][nf], 0, 0, 0);
      }
      __builtin_amdgcn_s_setprio(0);
    }

    // drain: logits += g[row,e] * (xW+b).  C/D: col=lane&15, row=(lane>>4)*4+rg
    f32x4 gq[2];
    #pragma unroll
    for (int mf = 0; mf < 2; ++mf)
      gq[mf] = *(const f32x4*)&gsh[e][wave * 32 + mf * 16 + (lane >> 4) * 4];
    #pragma unroll
    for (int mf = 0; mf < 2; ++mf)
      #pragma unroll
      for (int nf = 0; nf < 4; ++nf)
        #pragma unroll
        for (int rg = 0; rg < 4; ++rg)
          logits[mf][nf][rg] += gq[mf][rg] * acc[mf][nf][rg];

    buf ^= 1;
  }

  float* pout = partials + (size_t)eg * B_SZ * O_SZ + (size_t)row0 * O_SZ;
  #pragma unroll
  for (int mf = 0; mf < 2; ++mf)
    #pragma unroll
    for (int nf = 0; nf < 4; ++nf)
      #pragma unroll
      for (int rg = 0; rg < 4; ++rg) {
        int r = wave * 32 + mf * 16 + ((lane >> 4) << 2) + rg;
        int o = nf * 16 + (lane & 15);
        pout[(size_t)r * O_SZ + o] = logits[mf][nf][rg];
      }
}

// ---------------- reduce: sum partials + log_softmax (bias already in gemm) ----
__global__ __launch_bounds__(256)
void mtc_reduce(const float* __restrict__ partials, float* __restrict__ out) {
  int wave = threadIdx.x >> 6, lane = threadIdx.x & 63;
  int r = blockIdx.x * 4 + wave;                    // one 64-lane wave per row
  float s = 0.f;
  #pragma unroll
  for (int k = 0; k < EG_N; ++k)
    s += partials[(size_t)k * B_SZ * O_SZ + (size_t)r * O_SZ + lane];
  float m = s;
  #pragma unroll
  for (int off = 32; off; off >>= 1) m = fmaxf(m, __shfl_xor(m, off));
  float ex = expf(s - m), sum = ex;
  #pragma unroll
  for (int off = 32; off; off >>= 1) sum += __shfl_xor(sum, off);
  out[(size_t)r * O_SZ + lane] = s - m - logf(sum);
}

extern "C" void kernel_launch(void* const* d_in, const int* in_sizes, int n_in,
                              void* d_out, int out_size, void* d_ws, size_t ws_size,
                              hipStream_t stream) {
  const float* x    = (const float*)d_in[0];
  const float* ds   = (const float*)d_in[1];
  const float* ts   = (const float*)d_in[2];
  const float* W    = (const float*)d_in[3];
  const float* bias = (const float*)d_in[4];
  float* out = (float*)d_out;

  char* w = (char*)d_ws;
  __bf16* xb      = (__bf16*)(w);                   // 4 MB
  __bf16* wt      = (__bf16*)(w + (4ull  << 20));   // 8 MB
  float*  gT      = (float*) (w + (12ull << 20));   // 2 MB
  float*  parts   = (float*) (w + (14ull << 20));   // 16 MB

  prep_xg   <<<2048, 256, 0, stream>>>(x, xb, ds, ts, gT);
  prep_w    <<<1024, 256, 0, stream>>>(W, wt);
  mtc_gemm  <<< 256, 512, 0, stream>>>(xb, wt, gT, bias, parts);
  mtc_reduce<<<1024, 256, 0, stream>>>(parts, out);
}